// Round 1
// baseline (270.875 us; speedup 1.0000x reference)
//
#include <hip/hip_runtime.h>

// BeliefMatchingLoss: pred [8,19,512,512] f32 logits, target [8,512,512] int.
// loss = mean over valid pixels of COEF*KL(Dir(alpha)||Dir(1)) - (psi(a_ans)-psi(a0))

#define NCLS 19
#define HW (512 * 512)          // 262144 = 2^18
#define NPIX (8 * HW)           // 2097152
#define IGNORE_IDX 255
#define COEF 0.01f

__device__ __forceinline__ float fast_rcp(float x) {
    return __builtin_amdgcn_rcpf(x);
}

// digamma & lgamma for x>0 via shift-by-6 recurrence + asymptotic series (y>=6).
// |trunc err| < 3e-9 for both; fp32 rounding dominates (fine vs 0.1 scalar tol).
__device__ __forceinline__ void dg_lg(float a, float& dg, float& lg) {
    float x1 = a + 1.f, x2 = a + 2.f, x3 = a + 3.f, x4 = a + 4.f, x5 = a + 5.f;
    float p = a * x1 * x2 * x3 * x4 * x5;
    float rsum = fast_rcp(a) + fast_rcp(x1) + fast_rcp(x2) +
                 fast_rcp(x3) + fast_rcp(x4) + fast_rcp(x5);
    float y = a + 6.f;
    float r = fast_rcp(y);
    float r2 = r * r;
    float ln_y = __logf(y);
    // psi(y) = ln y - r/2 - r^2/12 + r^4/120 - r^6/252
    dg = ln_y - 0.5f * r
         - r2 * (0.0833333333f - r2 * (0.0083333333f - r2 * 0.0039682540f))
         - rsum;
    // lnGamma(y) = (y-1/2) ln y - y + ln(2pi)/2 + r/12 - r^3/360 + r^5/1260
    lg = (y - 0.5f) * ln_y - y + 0.91893853320467f
         + r * (0.0833333333f - r2 * (0.0027777778f - r2 * 0.00079365079f))
         - __logf(p);
}

__global__ __launch_bounds__(256) void bml_main(const float* __restrict__ pred,
                                                const int* __restrict__ target,
                                                double* __restrict__ ws) {
    int tid = blockIdx.x * blockDim.x + threadIdx.x;
    int nth = gridDim.x * blockDim.x;

    float local = 0.f;
    unsigned cnt = 0;

    for (int p = tid; p < NPIX; p += nth) {
        int b = p >> 18;           // p / HW
        int hw = p & (HW - 1);
        const float* base = pred + (size_t)b * NCLS * HW + hw;

        int t = target[p];
        bool ignore = (t == IGNORE_IDX);
        int tc = ignore ? 0 : t;

        float a0 = 0.f, slg = 0.f, s2 = 0.f, dg_ans = 0.f;
        #pragma unroll
        for (int c = 0; c < NCLS; ++c) {
            float a = __expf(base[(size_t)c * HW]);
            float dg, lg;
            dg_lg(a, dg, lg);
            a0 += a;
            slg += lg;
            s2 += (a - 1.f) * dg;
            if (c == tc) dg_ans = dg;
        }
        float dg0, lg0;
        dg_lg(a0, dg0, lg0);

        float ll = dg_ans - dg0;                       // digamma(a_ans)-digamma(a_zero)
        float loss1 = lg0 - slg;                       // gammaln(a0) - sum gammaln(a)
        float loss2 = s2 - dg0 * (a0 - (float)NCLS);   // sum (a-1)*(psi(a)-psi(a0))
        float loss = COEF * (loss1 + loss2) - ll;

        if (!ignore) { local += loss; cnt++; }
    }

    // wave(64) reduce
    #pragma unroll
    for (int off = 32; off; off >>= 1) {
        local += __shfl_down(local, off);
        cnt   += __shfl_down(cnt, off);
    }
    __shared__ float s_sum[4];
    __shared__ unsigned s_cnt[4];
    int lane = threadIdx.x & 63, wid = threadIdx.x >> 6;
    if (lane == 0) { s_sum[wid] = local; s_cnt[wid] = cnt; }
    __syncthreads();
    if (threadIdx.x == 0) {
        float bs = s_sum[0] + s_sum[1] + s_sum[2] + s_sum[3];
        unsigned bc = s_cnt[0] + s_cnt[1] + s_cnt[2] + s_cnt[3];
        atomicAdd(&ws[0], (double)bs);
        atomicAdd(&ws[1], (double)bc);
    }
}

__global__ void bml_finalize(const double* __restrict__ ws, float* __restrict__ out) {
    if (threadIdx.x == 0 && blockIdx.x == 0)
        out[0] = (float)(ws[0] / ws[1]);
}

extern "C" void kernel_launch(void* const* d_in, const int* in_sizes, int n_in,
                              void* d_out, int out_size, void* d_ws, size_t ws_size,
                              hipStream_t stream) {
    const float* pred = (const float*)d_in[0];
    const int* target = (const int*)d_in[1];
    float* out = (float*)d_out;
    double* ws = (double*)d_ws;

    hipMemsetAsync(d_ws, 0, 2 * sizeof(double), stream);

    const int block = 256;
    const int grid = 2048;   // 256 CU x 8 blocks; 4 pixels/thread grid-stride
    bml_main<<<grid, block, 0, stream>>>(pred, target, ws);
    bml_finalize<<<1, 64, 0, stream>>>(ws, out);
}

// Round 2
// 262.967 us; speedup vs baseline: 1.0301x; 1.0301x over previous
//
#include <hip/hip_runtime.h>

// BeliefMatchingLoss: pred [8,19,512,512] f32 logits, target [8,512,512] int.
// loss = mean over valid pixels of COEF*KL(Dir(alpha)||Dir(1)) - (psi(a_ans)-psi(a0))
//
// Math: shift-3 recurrence. For y = a+3, p = a(a+1)(a+2):
//   psi(a)    = psi(y) - (3a^2+6a+2)/p
//   lnGamma(a)= lnGamma(y) - ln p
// psi(y), lnGamma(y) via asymptotic series (y>=3, trunc err < 3e-7).
// Sum_c lnGamma(a_c) = Sum_c lnGamma(y_c) - ln(Prod_c p_c), product in fp64.
// Per channel trans ops: 1 exp + 1 rcp + 1 log  (was 1 exp + 6 rcp + 2 log).

#define NCLS 19
#define HW (512 * 512)          // 2^18
#define NPIX (8 * HW)           // 2097152
#define IGNORE_IDX 255

#define PC1 0.08333333333f      // 1/12
#define PC2 0.00833333333f      // 1/120
#define PC3 0.00396825397f      // 1/252
#define GL1 0.08333333333f      // 1/12
#define GL2 0.00277777778f      // 1/360
#define GL3 0.00079365079f      // 1/1260
#define HLN2PI 0.918938533205f  // ln(2*pi)/2
#define LN2F 0.693147180560f

__device__ __forceinline__ float fast_rcp(float x) { return __builtin_amdgcn_rcpf(x); }

struct Acc {
    float a0, s2, slgy, dgans;
    double ppd;
};

// one channel contribution for one pixel
__device__ __forceinline__ void chan(float x, int c, int tc, Acc& A) {
    float a  = __expf(x);
    float a1 = a + 1.f, a2 = a + 2.f, y = a + 3.f;
    float p  = a * a1 * a2;
    float rpy = fast_rcp(p * y);
    float r  = p * rpy;     // 1/y
    float rp = y * rpy;     // 1/p
    float q  = __fmaf_rn(a, __fmaf_rn(a, 3.f, 6.f), 2.f);  // 3a^2+6a+2
    float ly = __logf(y);
    float r2 = r * r;
    float psiy = ly - 0.5f * r - r2 * (PC1 - r2 * (PC2 - r2 * PC3));
    float psia = psiy - q * rp;
    A.s2 = __fmaf_rn(a - 1.f, psia, A.s2);
    A.a0 += a;
    float lgy = __fmaf_rn(y - 0.5f, ly, -y) + HLN2PI
                + r * (GL1 - r2 * (GL2 - r2 * GL3));
    A.slgy += lgy;
    A.ppd *= (double)p;
    A.dgans = (c == tc) ? psia : A.dgans;
}

__device__ __forceinline__ float finish(const Acc& A) {
    float a0 = A.a0;
    float a1 = a0 + 1.f, a2 = a0 + 2.f, y = a0 + 3.f;
    float p  = a0 * a1 * a2;
    float rpy = fast_rcp(p * y);
    float r  = p * rpy, rp = y * rpy;
    float q  = __fmaf_rn(a0, __fmaf_rn(a0, 3.f, 6.f), 2.f);
    float ly = __logf(y);
    float r2 = r * r;
    float psi0 = ly - 0.5f * r - r2 * (PC1 - r2 * (PC2 - r2 * PC3)) - q * rp;
    float lg0  = __fmaf_rn(y - 0.5f, ly, -y) + HLN2PI
                 + r * (GL1 - r2 * (GL2 - r2 * GL3)) - __logf(p);
    // ln of the fp64 product of p_c: exponent/mantissa split
    int hi = __double2hiint(A.ppd);
    int lo = __double2loint(A.ppd);
    int e  = ((hi >> 20) & 0x7FF) - 1023;
    double mant = __hiloint2double((hi & 0x000FFFFF) | 0x3FF00000, lo);  // [1,2)
    float lnpp = __logf((float)mant) + (float)e * LN2F;

    float ll    = A.dgans - psi0;
    float loss1 = lg0 - (A.slgy - lnpp);
    float loss2 = A.s2 - psi0 * (a0 - (float)NCLS);
    return 0.01f * (loss1 + loss2) - ll;
}

__global__ __launch_bounds__(256) void bml_main(const float* __restrict__ pred,
                                                const int* __restrict__ target,
                                                double* __restrict__ ws) {
    int g  = blockIdx.x * blockDim.x + threadIdx.x;  // pixel group, 4 px each
    int p4 = g << 2;
    int b  = p4 >> 18;
    int hw = p4 & (HW - 1);
    const float4* base = (const float4*)(pred + (size_t)b * NCLS * HW + hw);

    int4 t4 = *(const int4*)(target + p4);
    int tc0 = (t4.x == IGNORE_IDX) ? 0 : t4.x;
    int tc1 = (t4.y == IGNORE_IDX) ? 0 : t4.y;
    int tc2 = (t4.z == IGNORE_IDX) ? 0 : t4.z;
    int tc3 = (t4.w == IGNORE_IDX) ? 0 : t4.w;

    Acc A0 = {0.f, 0.f, 0.f, 0.f, 1.0};
    Acc A1 = {0.f, 0.f, 0.f, 0.f, 1.0};
    Acc A2 = {0.f, 0.f, 0.f, 0.f, 1.0};
    Acc A3 = {0.f, 0.f, 0.f, 0.f, 1.0};

    #pragma unroll 2
    for (int c = 0; c < NCLS; ++c) {
        float4 x = base[(size_t)c * (HW / 4)];
        chan(x.x, c, tc0, A0);
        chan(x.y, c, tc1, A1);
        chan(x.z, c, tc2, A2);
        chan(x.w, c, tc3, A3);
    }

    float l0 = finish(A0), l1 = finish(A1), l2 = finish(A2), l3 = finish(A3);

    float local = 0.f;
    unsigned cnt = 0;
    if (t4.x != IGNORE_IDX) { local += l0; cnt++; }
    if (t4.y != IGNORE_IDX) { local += l1; cnt++; }
    if (t4.z != IGNORE_IDX) { local += l2; cnt++; }
    if (t4.w != IGNORE_IDX) { local += l3; cnt++; }

    #pragma unroll
    for (int off = 32; off; off >>= 1) {
        local += __shfl_down(local, off);
        cnt   += __shfl_down(cnt, off);
    }
    __shared__ float s_sum[4];
    __shared__ unsigned s_cnt[4];
    int lane = threadIdx.x & 63, wid = threadIdx.x >> 6;
    if (lane == 0) { s_sum[wid] = local; s_cnt[wid] = cnt; }
    __syncthreads();
    if (threadIdx.x == 0) {
        float bs = s_sum[0] + s_sum[1] + s_sum[2] + s_sum[3];
        unsigned bc = s_cnt[0] + s_cnt[1] + s_cnt[2] + s_cnt[3];
        atomicAdd(&ws[0], (double)bs);
        atomicAdd(&ws[1], (double)bc);
    }
}

__global__ void bml_finalize(const double* __restrict__ ws, float* __restrict__ out) {
    if (threadIdx.x == 0 && blockIdx.x == 0)
        out[0] = (float)(ws[0] / ws[1]);
}

extern "C" void kernel_launch(void* const* d_in, const int* in_sizes, int n_in,
                              void* d_out, int out_size, void* d_ws, size_t ws_size,
                              hipStream_t stream) {
    const float* pred = (const float*)d_in[0];
    const int* target = (const int*)d_in[1];
    float* out = (float*)d_out;
    double* ws = (double*)d_ws;

    hipMemsetAsync(d_ws, 0, 2 * sizeof(double), stream);

    const int block = 256;
    const int grid = NPIX / (block * 4);  // 2048 blocks, 4 px/thread
    bml_main<<<grid, block, 0, stream>>>(pred, target, ws);
    bml_finalize<<<1, 64, 0, stream>>>(ws, out);
}